// Round 1
// baseline (1055.810 us; speedup 1.0000x reference)
//
#include <hip/hip_runtime.h>
#include <stdint.h>

typedef unsigned int u32;
typedef unsigned long long u64;

#define KSEL 6000      // pre_nms_limit
#define PC   1000      // proposal_count
#define NW   94        // ceil(KSEL/64) removal-mask words
#define CAP  8000      // LDS collection cap (>= KSEL, < 8126 so ctrl/hist tail is safe)

__device__ inline u64 shfl64(u64 v, int src) {
    int lo = __shfl((int)(u32)(v & 0xFFFFFFFFULL), src);
    int hi = __shfl((int)(u32)(v >> 32), src);
    return ((u64)(u32)hi << 32) | (u32)lo;
}

// ---------------- K0: order-preserving score keys ----------------
__global__ void k_keys(const float* __restrict__ probs, u32* __restrict__ keys, int total) {
    int i = blockIdx.x * 256 + threadIdx.x;
    if (i >= total) return;
    u32 u = __float_as_uint(probs[(size_t)i * 2 + 1]);   // probs[..][1]
    u = (u & 0x80000000u) ? ~u : (u | 0x80000000u);      // monotone map: float order -> uint order
    keys[i] = u;
}

// ---------------- K1: per-sample radix-select + stable sort + box decode ----------------
__global__ __launch_bounds__(1024)
void k_select(const float* __restrict__ probs, const float* __restrict__ deltas,
              const float* __restrict__ anchors, const u32* __restrict__ keys,
              float* __restrict__ boxes_sel, float* __restrict__ scores_sel, int A)
{
    __shared__ u64 sbuf[8192];                // 64 KiB, also aliases hist/ctrl in its tail
    u32* hist = (u32*)(sbuf + 8128);          // 256 u32
    u32* ctrl = (u32*)(sbuf + 8126);          // ctrl[0]=chosen byte, ctrl[1]=collect counter
    const int tid = threadIdx.x;
    const int b = blockIdx.x;
    const u32* kb = keys + (size_t)b * A;

    // 4-level radix select: find exact 32-bit pivot T s.t. count(key>T) < KSEL <= count(key>=T)
    u32 pfx = 0;
    int rem = KSEL;                            // authoritative only on thread 0
    for (int l = 0; l < 4; ++l) {
        int shift = 24 - 8 * l;
        for (int h = tid; h < 256; h += 1024) hist[h] = 0;
        __syncthreads();
        for (int a = tid; a < A; a += 1024) {
            u32 k = kb[a];
            if (((u64)k >> (shift + 8)) == (u64)pfx)
                atomicAdd(&hist[(k >> shift) & 0xFFu], 1u);
        }
        __syncthreads();
        if (tid == 0) {
            int cum = 0, chosen = 0;
            for (int bin = 255; bin >= 0; --bin) {
                int c = (int)hist[bin];
                if (cum + c >= rem) { chosen = bin; break; }
                cum += c;
            }
            rem -= cum;
            ctrl[0] = (u32)chosen;
        }
        __syncthreads();
        pfx = (pfx << 8) | ctrl[0];
        __syncthreads();
    }
    const u32 T = pfx;

    // collect all keys >= T as (~key, index): ascending sort == (score desc, index asc)
    if (tid == 0) ctrl[1] = 0;
    __syncthreads();
    for (int a = tid; a < A; a += 1024) {
        u32 k = kb[a];
        if (k >= T) {
            u32 pos = atomicAdd(&ctrl[1], 1u);
            if (pos < CAP) sbuf[pos] = ((u64)(~k) << 32) | (u32)a;
        }
    }
    __syncthreads();
    int cnt = (int)ctrl[1]; if (cnt > CAP) cnt = CAP;
    __syncthreads();                           // everyone read ctrl before pad clobbers tail
    for (int i = cnt + tid; i < 8192; i += 1024) sbuf[i] = ~0ULL;

    // bitonic sort ascending, N=8192
    for (int kk = 2; kk <= 8192; kk <<= 1)
        for (int jj = kk >> 1; jj > 0; jj >>= 1) {
            __syncthreads();
            for (int i = tid; i < 8192; i += 1024) {
                int ixj = i ^ jj;
                if (ixj > i) {
                    u64 x = sbuf[i], y = sbuf[ixj];
                    bool up = ((i & kk) == 0);
                    if ((x > y) == up) { sbuf[i] = y; sbuf[ixj] = x; }
                }
            }
        }
    __syncthreads();

    // decode + clip the top-KSEL boxes in rank order
    for (int s = tid; s < KSEL; s += 1024) {
        u64 ck = sbuf[s];
        int a = (int)(u32)ck;
        float score = probs[((size_t)b * A + a) * 2 + 1];
        float4 an = ((const float4*)anchors)[a];                 // y1,x1,y2,x2
        float4 dl = ((const float4*)deltas)[(size_t)b * A + a];
        float h = an.z - an.x, w = an.w - an.y;
        float cy = an.x + 0.5f * h + dl.x * 0.1f * h;            // BBOX_STD_DEV = .1,.1,.2,.2
        float cx = an.y + 0.5f * w + dl.y * 0.1f * w;
        h *= expf(dl.z * 0.2f);
        w *= expf(dl.w * 0.2f);
        float y1 = cy - 0.5f * h, x1 = cx - 0.5f * w;
        float y2 = y1 + h,        x2 = x1 + w;
        y1 = fminf(fmaxf(y1, 0.f), 1024.f);
        x1 = fminf(fmaxf(x1, 0.f), 1024.f);
        y2 = fminf(fmaxf(y2, 0.f), 1024.f);
        x2 = fminf(fmaxf(x2, 0.f), 1024.f);
        ((float4*)boxes_sel)[(size_t)b * KSEL + s] = make_float4(y1, x1, y2, x2);
        scores_sel[(size_t)b * KSEL + s] = score;
    }
}

// ---------------- K2: 64-bit suppression mask matrix ----------------
__global__ __launch_bounds__(64)
void k_iou(const float* __restrict__ boxes_sel, u64* __restrict__ mask)
{
    __shared__ float4 rowb[64];
    int t = threadIdx.x;
    int bi = blockIdx.x, bj = blockIdx.y, b = blockIdx.z;
    const float4* boxes = (const float4*)boxes_sel + (size_t)b * KSEL;
    int ri = bi * 64 + t;
    int j  = bj * 64 + t;
    rowb[t] = (ri < KSEL) ? boxes[ri] : make_float4(0.f, 0.f, 0.f, 0.f);
    float4 cb = (j < KSEL) ? boxes[j] : make_float4(0.f, 0.f, 0.f, 0.f);
    float areaC = (cb.z - cb.x) * (cb.w - cb.y);
    __syncthreads();
    u64 myword = 0;
    for (int r = 0; r < 64; ++r) {
        float4 rb = rowb[r];
        float areaR = (rb.z - rb.x) * (rb.w - rb.y);
        float iy1 = fmaxf(rb.x, cb.x), ix1 = fmaxf(rb.y, cb.y);
        float iy2 = fminf(rb.z, cb.z), ix2 = fminf(rb.w, cb.w);
        float inter = fmaxf(iy2 - iy1, 0.f) * fmaxf(ix2 - ix1, 0.f);
        float uni = fmaxf(areaR + areaC - inter, 1e-10f);
        bool sup = (j < KSEL) && (inter > 0.7f * uni);           // iou > NMS_THRESHOLD
        u64 word = __ballot(sup ? 1 : 0);
        if (r == t) myword = word;
    }
    if (ri < KSEL) mask[((size_t)b * KSEL + ri) * NW + bj] = myword;
}

// ---------------- K3: serial greedy scan, 1 wave/sample, register-prefetched ----------------
__global__ __launch_bounds__(64)
void k_nms(const u64* __restrict__ mask, int* __restrict__ keepidx, int* __restrict__ nkept)
{
    const int lane = threadIdx.x;
    const int b = blockIdx.x;
    const u64* mb = mask + (size_t)b * KSEL * NW;
    int* ki = keepidx + b * PC;

    const int P = 16;                 // prefetch depth; KSEL % P == 0
    u64 pf0[P], pf1[P];               // lane l holds row words l and 64+l (l<30)
#pragma unroll
    for (int p = 0; p < P; ++p) {
        const u64* row = mb + (size_t)p * NW;
        pf0[p] = row[lane];
        pf1[p] = (lane < NW - 64) ? row[64 + lane] : 0ULL;
    }
    u64 remv0 = 0, remv1 = 0, curw = 0;
    int kept = 0;
    bool done = false;
    for (int i0 = 0; i0 < KSEL; i0 += P) {
#pragma unroll
        for (int p = 0; p < P; ++p) {
            int i = i0 + p;
            if (!done) {
                int wi = i >> 6, bit = i & 63;
                if (bit == 0)
                    curw = (wi < 64) ? shfl64(remv0, wi) : shfl64(remv1, wi - 64);
                if (!((curw >> bit) & 1ULL)) {
                    remv0 |= pf0[p];
                    remv1 |= pf1[p];
                    u64 wrow = (wi < 64) ? shfl64(pf0[p], wi) : shfl64(pf1[p], wi - 64);
                    curw |= wrow;
                    if (lane == 0) ki[kept] = i;
                    ++kept;
                    if (kept >= PC) done = true;   // n = min(total,1000); later slots never emitted
                }
                int nx = i + P;
                if (!done && nx < KSEL) {
                    const u64* row = mb + (size_t)nx * NW;
                    pf0[p] = row[lane];
                    pf1[p] = (lane < NW - 64) ? row[64 + lane] : 0ULL;
                }
            }
        }
        if (done) break;
    }
    if (lane == 0) nkept[b] = kept;
}

// ---------------- K4: gather kept -> output (zero tail, n as float) ----------------
__global__ void k_out(const float* __restrict__ boxes_sel, const float* __restrict__ scores_sel,
                      const int* __restrict__ keepidx, const int* __restrict__ nkept,
                      float* __restrict__ out, int B)
{
    int idx = blockIdx.x * 256 + threadIdx.x;
    int nb = B * PC * 4;       // boxes region
    int ns = B * PC;           // scores region
    if (idx < nb) {
        int b = idx / (PC * 4);
        int r = idx % (PC * 4);
        int s = r >> 2, c = r & 3;
        float v = 0.f;
        if (s < nkept[b]) {
            int i = keepidx[b * PC + s];
            v = boxes_sel[((size_t)b * KSEL + i) * 4 + c] * (1.0f / 1024.0f);
        }
        out[idx] = v;
    } else if (idx < nb + ns) {
        int r = idx - nb;
        int b = r / PC, s = r % PC;
        float v = 0.f;
        if (s < nkept[b]) v = scores_sel[(size_t)b * KSEL + keepidx[b * PC + s]];
        out[idx] = v;
    } else if (idx < nb + ns + B) {
        int b = idx - nb - ns;
        out[idx] = (float)nkept[b];
    }
}

extern "C" void kernel_launch(void* const* d_in, const int* in_sizes, int n_in,
                              void* d_out, int out_size, void* d_ws, size_t ws_size,
                              hipStream_t stream)
{
    const float* probs   = (const float*)d_in[0];
    const float* deltas  = (const float*)d_in[1];
    const float* anchors = (const float*)d_in[2];
    int A = in_sizes[2] / 4;            // anchors: (A,4)
    int B = in_sizes[0] / (2 * A);      // probs:   (B,A,2)

    char* w = (char*)d_ws;
    size_t off = 0;
    u32* keys = (u32*)(w + off);        off += (size_t)B * A * sizeof(u32);
    off = (off + 15) & ~(size_t)15;
    float* boxes_sel = (float*)(w + off);  off += (size_t)B * KSEL * 4 * sizeof(float);
    float* scores_sel = (float*)(w + off); off += (size_t)B * KSEL * sizeof(float);
    int* keepidx = (int*)(w + off);        off += (size_t)B * PC * sizeof(int);
    int* nkept = (int*)(w + off);          off += (size_t)B * sizeof(int);
    off = (off + 15) & ~(size_t)15;
    u64* mask = (u64*)(w + off);           off += (size_t)B * KSEL * NW * sizeof(u64);
    // total ws use ~22.8 MB

    int total = B * A;
    k_keys<<<(total + 255) / 256, 256, 0, stream>>>(probs, keys, total);
    k_select<<<B, 1024, 0, stream>>>(probs, deltas, anchors, keys, boxes_sel, scores_sel, A);
    k_iou<<<dim3(NW, NW, B), 64, 0, stream>>>(boxes_sel, mask);
    k_nms<<<B, 64, 0, stream>>>(mask, keepidx, nkept);
    int outn = B * (PC * 4 + PC + 1);
    k_out<<<(outn + 255) / 256, 256, 0, stream>>>(boxes_sel, scores_sel, keepidx, nkept,
                                                  (float*)d_out, B);
}